// Round 10
// baseline (1210.754 us; speedup 1.0000x reference)
//
#include <hip/hip_runtime.h>

#define NN 8192
#define STEPS 128
#define CLAMP_V 0.999f
#define WPR 1024   // packed 4-bit words per row (8192/8)
#define NBLK 256
#define TPB 1024

typedef unsigned long long ull;

#if __has_builtin(__builtin_amdgcn_sdot4)
#define DOT4(a, b, c) __builtin_amdgcn_sdot4((int)(a), (int)(b), (c), false)
#else
__device__ __forceinline__ int dot4_fb(int a, int b, int c) {
#pragma unroll
  for (int i = 0; i < 4; ++i)
    c += ((int)(signed char)(a >> (8 * i))) * ((int)(signed char)(b >> (8 * i)));
  return c;
}
#define DOT4(a, b, c) dot4_fb((int)(a), (int)(b), (c))
#endif

#if __has_builtin(__builtin_amdgcn_perm)
#define PERM(a, b, s) __builtin_amdgcn_perm((a), (b), (s))
#else
__device__ __forceinline__ unsigned perm_fb(unsigned a, unsigned b, unsigned s) {
  unsigned long long v = ((unsigned long long)a << 32) | b;
  unsigned r = 0;
#pragma unroll
  for (int i = 0; i < 4; ++i) r |= ((unsigned)(v >> (8 * ((s >> (8 * i)) & 7))) & 0xFF) << (8 * i);
  return r;
}
#define PERM(a, b, s) perm_fb((a), (b), (s))
#endif

// =============== int4 quantization -> per-wave-contiguous layout (R7) ===============
// Nibble order per word: {c0,c4,c1,c5,c2,c6,c3,c7}; lo=(w<<4)&0xF0F0F0F0={c0..c3}*16,
// hi=w&0xF0F0F0F0={c4..c7}*16. scales[row]=rowmax/(7*16).
// Wave wv of block b owns rows 32b+2wv (ab=0), +1 (ab=1); lane l uses word seg*64+l.
// Lane's 32 words contiguous: Kq[((b*16+wv)*64 + l)*32 + ab*16 + seg]
// => per-step K reload = 8 coalesced dwordx4 per lane.
__global__ __launch_bounds__(256) void quant4_kernel(const float* __restrict__ K,
                                                     unsigned* __restrict__ Kq,
                                                     float* __restrict__ scales) {
  const int row = blockIdx.x;
  const int tid = threadIdx.x;
  const int wave = tid >> 6, lane = tid & 63;
  const size_t base = (size_t)row * NN;

  float4 va[4], vb[4];
  float mx = 0.f;
#pragma unroll
  for (int g = 0; g < 4; ++g) {
    const size_t o = base + (size_t)(g * 256 + tid) * 8;
    va[g] = *(const float4*)(K + o);
    vb[g] = *(const float4*)(K + o + 4);
    mx = fmaxf(mx, fmaxf(fmaxf(fabsf(va[g].x), fabsf(va[g].y)),
                         fmaxf(fabsf(va[g].z), fabsf(va[g].w))));
    mx = fmaxf(mx, fmaxf(fmaxf(fabsf(vb[g].x), fabsf(vb[g].y)),
                         fmaxf(fabsf(vb[g].z), fabsf(vb[g].w))));
  }
#pragma unroll
  for (int off = 32; off > 0; off >>= 1) mx = fmaxf(mx, __shfl_xor(mx, off));
  __shared__ float wm[4];
  if (lane == 0) wm[wave] = mx;
  __syncthreads();
  mx = fmaxf(fmaxf(wm[0], wm[1]), fmaxf(wm[2], wm[3]));

  const float inv = (mx > 0.f) ? 7.f / mx : 0.f;
  if (tid == 0) scales[row] = mx / 112.f;   // rowmax/(7*16)

  const int b = row >> 5, wv = (row & 31) >> 1, ab = row & 1;

#pragma unroll
  for (int g = 0; g < 4; ++g) {
    int qa[4], qb[4];
    const float a4[4] = {va[g].x, va[g].y, va[g].z, va[g].w};
    const float b4[4] = {vb[g].x, vb[g].y, vb[g].z, vb[g].w};
#pragma unroll
    for (int i = 0; i < 4; ++i) {
      qa[i] = max(-7, min(7, __float2int_rn(a4[i] * inv)));
      qb[i] = max(-7, min(7, __float2int_rn(b4[i] * inv)));
    }
    unsigned w = 0;
#pragma unroll
    for (int i = 0; i < 4; ++i) {
      w |= ((unsigned)(qa[i] & 0xF)) << (8 * i);        // c_i at nibble 2i
      w |= ((unsigned)(qb[i] & 0xF)) << (8 * i + 4);    // c_{4+i} at nibble 2i+1
    }
    const int widx = g * 256 + tid;
    const int seg = widx >> 6, l = widx & 63;
    Kq[(size_t)((b * 16 + wv) * 64 + l) * 32 + ab * 16 + seg] = w;
  }
}

// =============== prep: build payload plane_0 (u32/pair), zero flags ===============
// Payload u32 for pair p (rows 2p,2p+1): re0 | im0<<8 | re1<<16 | im1<<24.
__global__ __launch_bounds__(256) void prep_kernel(const float* __restrict__ z,
                                                   unsigned* __restrict__ pz0,
                                                   int* __restrict__ flags,
                                                   float* __restrict__ scz) {
  const int tid = threadIdx.x;
  const int wave = tid >> 6, lane = tid & 63;
  float4 buf[16];
  float mx = 0.f;
#pragma unroll
  for (int j = 0; j < 16; ++j) {
    buf[j] = *(const float4*)(z + tid * 64 + j * 4);
    mx = fmaxf(mx, fmaxf(fmaxf(fabsf(buf[j].x), fabsf(buf[j].y)),
                         fmaxf(fabsf(buf[j].z), fabsf(buf[j].w))));
  }
#pragma unroll
  for (int off = 32; off > 0; off >>= 1) mx = fmaxf(mx, __shfl_xor(mx, off));
  __shared__ float wm[4];
  if (lane == 0) wm[wave] = mx;
  __syncthreads();
  mx = fmaxf(fmaxf(wm[0], wm[1]), fmaxf(wm[2], wm[3]));
  const float q = (mx > 0.f) ? 127.f / mx : 0.f;
  if (tid == 0) scz[0] = mx / 127.f;
  flags[tid] = 0;   // one flag per block; visible when persist launches
#pragma unroll
  for (int j = 0; j < 16; ++j) {
    const int p = tid * 16 + j;
    const unsigned a = (unsigned)(max(-127, min(127, __float2int_rn(buf[j].x * q)))) & 0xFFu;
    const unsigned b = (unsigned)(max(-127, min(127, __float2int_rn(buf[j].y * q)))) & 0xFFu;
    const unsigned c = (unsigned)(max(-127, min(127, __float2int_rn(buf[j].z * q)))) & 0xFFu;
    const unsigned d = (unsigned)(max(-127, min(127, __float2int_rn(buf[j].w * q)))) & 0xFFu;
    pz0[p] = a | (b << 8) | (c << 16) | (d << 24);
  }
}

// =============== persistent kernel: 2-hop exchange (flags + bulk payload) ===============
// 256 blocks x 1024 thr (16 waves). Wave w owns pair 16b+w (rows 32b+2w,+1).
// Per step: prefetch K (8 dwordx4) -> [wave 15 only: poll 256 flags >= s
// (4 coalesced loads/lane, selective re-read) -> LDS gflag=s] -> all waves
// spin on LDS gflag (zero fabric) -> each thread bulk-loads its 2 payload u64
// (16B contiguous, ONCE) -> v_perm unpack -> ds_write plane -> SYNC-A -> dot
// 16 segs (K in regs) -> butterfly -> lane-split update -> pub[wave] to LDS
// -> SYNC-B -> wave 0: 16-lane payload store (64B) + release flag[b]=s+1.
// Safety: flags monotonic; all flags >= s  =>  every block stored plane s
// => every block finished reading plane s-1 => overwriting parity (s+1)&1
// (holding plane s-1) is safe. Payload region [16b,16b+16) written only by
// its owner block => flag >= s implies region holds step-s data exactly.
__global__ __launch_bounds__(TPB, 4)
void persist_kernel(const unsigned* __restrict__ Kq, const float* __restrict__ scales,
                    const float* __restrict__ z_in,
                    unsigned* __restrict__ pz0, unsigned* __restrict__ pz1,
                    int* __restrict__ flags,
                    const float* __restrict__ scz_p,
                    const float* __restrict__ omega_p, const float* __restrict__ dt_p,
                    float* __restrict__ out) {
  const int tid = threadIdx.x;
  const int wave = tid >> 6, lane = tid & 63;
  const int rowA = blockIdx.x * 32 + wave * 2;

  __shared__ ull lds_re[2][1024];   // 16 KiB: double-buffered re plane
  __shared__ ull lds_im[2][1024];   // 16 KiB: double-buffered im plane
  __shared__ unsigned pub[16];      // per-wave packed payload for this block
  __shared__ int gflag;             // broadcast: flags verified up to step gflag
  if (tid == 0) gflag = -1;
  __syncthreads();   // one-time init barrier only

  // ---- per-lane z state: even lanes own row A, odd lanes own row B ----
  const int isB = lane & 1;
  float zr_s = z_in[2 * rowA + 2 * isB];
  float zi_s = z_in[2 * rowA + 2 * isB + 1];
  const float mySc = scales[rowA + isB];
  const float omega = *omega_p, dt = *dt_p;
  const float inv2n = 1.0f / (2.0f * (float)NN);
  const float sz0 = *scz_p;

  // lane's 32 K-words (rowA segs 0..15, rowB segs 0..15), contiguous
  const uint4* kp = (const uint4*)(Kq + (size_t)((blockIdx.x * 16 + wave) * 64 + lane) * 32);

  for (int s = 0; s < STEPS; ++s) {
    const int buf = s & 1;

    // ---- issue K prefetch first: completes under the flag wait ----
    uint4 kv[8];
#pragma unroll
    for (int r = 0; r < 8; ++r) kv[r] = kp[r];

    // ---- wave 15: poll the 256 block flags (1 KB sweep, selective) ----
    if (wave == 15) {
      bool k0 = false, k1 = false, k2 = false, k3 = false;
      for (;;) {
        if (!k0) k0 = __hip_atomic_load(&flags[lane], __ATOMIC_RELAXED,
                                        __HIP_MEMORY_SCOPE_AGENT) >= s;
        if (!k1) k1 = __hip_atomic_load(&flags[lane + 64], __ATOMIC_RELAXED,
                                        __HIP_MEMORY_SCOPE_AGENT) >= s;
        if (!k2) k2 = __hip_atomic_load(&flags[lane + 128], __ATOMIC_RELAXED,
                                        __HIP_MEMORY_SCOPE_AGENT) >= s;
        if (!k3) k3 = __hip_atomic_load(&flags[lane + 192], __ATOMIC_RELAXED,
                                        __HIP_MEMORY_SCOPE_AGENT) >= s;
        if (__all(k0 && k1 && k2 && k3)) break;
        __builtin_amdgcn_s_sleep(1);   // ~64 cyc detect quantum
      }
      if (lane == 0)
        __hip_atomic_store(&gflag, s, __ATOMIC_RELEASE, __HIP_MEMORY_SCOPE_WORKGROUP);
    }
    // ---- all waves: wait broadcast (LDS spin, zero fabric traffic) ----
    while (__hip_atomic_load(&gflag, __ATOMIC_ACQUIRE, __HIP_MEMORY_SCOPE_WORKGROUP) < s)
      __builtin_amdgcn_s_sleep(1);

    // ---- bulk payload load: thread tid covers plane word tid (pairs 4t..4t+3) ----
    {
      const ull* pzc = (const ull*)((s & 1) ? pz1 : pz0);
      const ull t0 = __hip_atomic_load(&pzc[2 * tid], __ATOMIC_RELAXED,
                                       __HIP_MEMORY_SCOPE_AGENT);
      const ull t1 = __hip_atomic_load(&pzc[2 * tid + 1], __ATOMIC_RELAXED,
                                       __HIP_MEMORY_SCOPE_AGENT);
      const unsigned lo0 = (unsigned)t0, lo1 = (unsigned)(t0 >> 32);
      const unsigned lo2 = (unsigned)t1, lo3 = (unsigned)(t1 >> 32);
      const unsigned re0123 = PERM(lo1, lo0, 0x06040200u);
      const unsigned re4567 = PERM(lo3, lo2, 0x06040200u);
      const unsigned im0123 = PERM(lo1, lo0, 0x07050301u);
      const unsigned im4567 = PERM(lo3, lo2, 0x07050301u);
      lds_re[buf][tid] = (ull)re0123 | ((ull)re4567 << 32);
      lds_im[buf][tid] = (ull)im0123 | ((ull)im4567 << 32);
    }
    __syncthreads();   // SYNC-A: full plane staged

    // ---- dot: both rows, all 16 segs; K from registers ----
    int srA = 0, siA = 0, srB = 0, siB = 0;
#pragma unroll
    for (int seg = 0; seg < 16; ++seg) {
      const ull zr = lds_re[buf][seg * 64 + lane];   // 8B lane stride: conflict-free
      const ull zi = lds_im[buf][seg * 64 + lane];
      const unsigned zrl = (unsigned)zr, zrh = (unsigned)(zr >> 32);
      const unsigned zil = (unsigned)zi, zih = (unsigned)(zi >> 32);
      const uint4 ka4 = kv[seg >> 2];
      const uint4 kb4 = kv[4 + (seg >> 2)];
      const unsigned wA = (seg & 3) == 0 ? ka4.x : (seg & 3) == 1 ? ka4.y
                        : (seg & 3) == 2 ? ka4.z : ka4.w;
      const unsigned wB = (seg & 3) == 0 ? kb4.x : (seg & 3) == 1 ? kb4.y
                        : (seg & 3) == 2 ? kb4.z : kb4.w;
      const unsigned loA = (wA << 4) & 0xF0F0F0F0u, hiA = wA & 0xF0F0F0F0u;
      const unsigned loB = (wB << 4) & 0xF0F0F0F0u, hiB = wB & 0xF0F0F0F0u;
      srA = DOT4(loA, zrl, srA); srA = DOT4(hiA, zrh, srA);
      siA = DOT4(loA, zil, siA); siA = DOT4(hiA, zih, siA);
      srB = DOT4(loB, zrl, srB); srB = DOT4(hiB, zrh, srB);
      siB = DOT4(loB, zil, siB); siB = DOT4(hiB, zih, siB);
    }

    // ---- exact integer wave butterfly -> lane-uniform sums ----
#pragma unroll
    for (int off = 32; off > 0; off >>= 1) {
      srA += __shfl_xor(srA, off); siA += __shfl_xor(siA, off);
      srB += __shfl_xor(srB, off); siB += __shfl_xor(siB, off);
    }

    // ---- lane-split update: even lanes row A, odd lanes row B (same op order) ----
    const int sr = isB ? srB : srA;
    const int si = isB ? siB : siA;
    const float sz = (s == 0) ? sz0 : (1.f / 127.f);
    const float fac = mySc * sz;
    const float Wr = (float)sr * fac, Wi = (float)si * fac;
    const float z2r = zr_s * zr_s - zi_s * zi_s;
    const float z2i = 2.0f * zr_s * zi_s;
    const float t1r = -inv2n * (Wr * z2r + Wi * z2i);
    const float t1i = -inv2n * (Wr * z2i - Wi * z2r);
    float nr = zr_s + dt * (t1r + omega * zr_s + inv2n * Wr);
    float ni = zi_s + dt * (t1i + omega * zi_s + inv2n * Wi);
    const float a = sqrtf(nr * nr + ni * ni);
    if (a >= CLAMP_V) { nr = nr / a * CLAMP_V; ni = ni / a * CLAMP_V; }
    zr_s = nr; zi_s = ni;

    if (s == STEPS - 1) {
      float fr = nr, fi = ni;
      const float n2 = sqrtf(fr * fr + fi * fi);
      if (n2 >= CLAMP_V) { fr = fr / n2 * CLAMP_V; fi = fi / n2 * CLAMP_V; }
      const float frB = __shfl(fr, 1);
      const float fiB = __shfl(fi, 1);
      if (lane == 0) {
        float4 o; o.x = fr; o.y = fi; o.z = frB; o.w = fiB;
        *(float4*)(out + 2 * rowA) = o;   // rows A,B contiguous, 16B-aligned
      }
    } else {
      const unsigned pr = (unsigned)__float2int_rn(nr * 127.f) & 0xFFu;
      const unsigned pi = (unsigned)__float2int_rn(ni * 127.f) & 0xFFu;
      const unsigned half = pr | (pi << 8);      // even: A bytes, odd: B bytes
      const unsigned other = __shfl_xor(half, 1);
      if (lane == 0) pub[wave] = half | (other << 16);
    }
    __syncthreads();   // SYNC-B: pub[] complete; plane-s reads closed

    // ---- wave 0: publish block payload (64B) + release generation flag ----
    if (s < STEPS - 1 && wave == 0 && lane < 16) {
      unsigned* pzn = (s & 1) ? pz0 : pz1;
      __hip_atomic_store(&pzn[16 * blockIdx.x + lane], pub[lane],
                         __ATOMIC_RELAXED, __HIP_MEMORY_SCOPE_AGENT);
      if (lane == 0)
        __hip_atomic_store(&flags[blockIdx.x], s + 1,
                           __ATOMIC_RELEASE, __HIP_MEMORY_SCOPE_AGENT);
    }
  }
}

// =============== f32 fallback (no workspace) ===============
__global__ __launch_bounds__(256, 2)
void step_f32(const float* __restrict__ K,
              const float* __restrict__ z_old, float* __restrict__ z_new,
              const float* __restrict__ omega_p, const float* __restrict__ dt_p) {
  const int tid = threadIdx.x;
  const int wave = tid >> 6, lane = tid & 63;
  const int row0 = blockIdx.x * 8;
  __shared__ float red[4][16];
  float ar[8] = {0, 0, 0, 0, 0, 0, 0, 0};
  float ai[8] = {0, 0, 0, 0, 0, 0, 0, 0};
  const int cbase = wave * 2048 + lane * 8;
#pragma unroll
  for (int it = 0; it < 4; ++it) {
    const int c = cbase + it * 512;
    const float4 zA = *(const float4*)(z_old + 2 * c + 0);
    const float4 zB = *(const float4*)(z_old + 2 * c + 4);
    const float4 zC = *(const float4*)(z_old + 2 * c + 8);
    const float4 zD = *(const float4*)(z_old + 2 * c + 12);
#pragma unroll
    for (int r = 0; r < 8; ++r) {
      const float* kp = K + (size_t)(row0 + r) * NN + c;
      const float4 ka = *(const float4*)kp;
      const float4 kb = *(const float4*)(kp + 4);
      float sr = ar[r], si = ai[r];
      sr = fmaf(ka.x, zA.x, sr); si = fmaf(ka.x, zA.y, si);
      sr = fmaf(ka.y, zA.z, sr); si = fmaf(ka.y, zA.w, si);
      sr = fmaf(ka.z, zB.x, sr); si = fmaf(ka.z, zB.y, si);
      sr = fmaf(ka.w, zB.z, sr); si = fmaf(ka.w, zB.w, si);
      sr = fmaf(kb.x, zC.x, sr); si = fmaf(kb.x, zC.y, si);
      sr = fmaf(kb.y, zC.z, sr); si = fmaf(kb.y, zC.w, si);
      sr = fmaf(kb.z, zD.x, sr); si = fmaf(kb.z, zD.y, si);
      sr = fmaf(kb.w, zD.z, sr); si = fmaf(kb.w, zD.w, si);
      ar[r] = sr; ai[r] = si;
    }
  }
#pragma unroll
  for (int off = 32; off > 0; off >>= 1) {
#pragma unroll
    for (int r = 0; r < 8; ++r) {
      ar[r] += __shfl_xor(ar[r], off);
      ai[r] += __shfl_xor(ai[r], off);
    }
  }
  if (lane == 0) {
#pragma unroll
    for (int r = 0; r < 8; ++r) {
      red[wave][2 * r + 0] = ar[r];
      red[wave][2 * r + 1] = ai[r];
    }
  }
  __syncthreads();
  if (tid < 8) {
    const float Wr = red[0][2 * tid] + red[1][2 * tid] + red[2][2 * tid] + red[3][2 * tid];
    const float Wi = red[0][2 * tid + 1] + red[1][2 * tid + 1] +
                     red[2][2 * tid + 1] + red[3][2 * tid + 1];
    const int row = row0 + tid;
    const float omega = *omega_p;
    const float dt = *dt_p;
    const float inv2n = 1.0f / (2.0f * (float)NN);
    const float zr = z_old[2 * row];
    const float zi = z_old[2 * row + 1];
    const float z2r = zr * zr - zi * zi;
    const float z2i = 2.0f * zr * zi;
    const float t1r = -inv2n * (Wr * z2r + Wi * z2i);
    const float t1i = -inv2n * (Wr * z2i - Wi * z2r);
    float nr = zr + dt * (t1r + omega * zr + inv2n * Wr);
    float ni = zi + dt * (t1i + omega * zi + inv2n * Wi);
    const float a = sqrtf(nr * nr + ni * ni);
    if (a >= CLAMP_V) { nr = nr / a * CLAMP_V; ni = ni / a * CLAMP_V; }
    z_new[2 * row] = nr;
    z_new[2 * row + 1] = ni;
  }
}

__global__ __launch_bounds__(256) void finalize_kernel(const float* __restrict__ z,
                                                       float* __restrict__ out) {
  int i = blockIdx.x * blockDim.x + threadIdx.x;
  if (i < NN) {
    float x = z[2 * i], y = z[2 * i + 1];
    float n = sqrtf(x * x + y * y);
    if (n >= CLAMP_V) { x = x / n * CLAMP_V; y = y / n * CLAMP_V; }
    out[2 * i] = x;
    out[2 * i + 1] = y;
  }
}

extern "C" void kernel_launch(void* const* d_in, const int* in_sizes, int n_in,
                              void* d_out, int out_size, void* d_ws, size_t ws_size,
                              hipStream_t stream) {
  const float* z_in = (const float*)d_in[0];      // [8192,2] f32
  const float* K = (const float*)d_in[1];         // [8192,8192] f32
  const float* omega_p = (const float*)d_in[2];   // scalar f32
  const float* dt_p = (const float*)d_in[3];      // scalar f32
  float* out = (float*)d_out;

  char* ws = (char*)d_ws;
  const size_t kq_bytes = (size_t)NN * WPR * sizeof(unsigned);   // 32 MiB
  const size_t sc_bytes = (size_t)NN * sizeof(float);            // 32 KiB
  const size_t pz_bytes = (size_t)(NN / 2) * sizeof(unsigned);   // 16 KiB each
  const size_t fl_bytes = (size_t)NBLK * sizeof(int);            // 1 KiB
  const size_t need = kq_bytes + sc_bytes + 2 * pz_bytes + fl_bytes + 256;

  if (ws_size >= need) {
    size_t off = 0;
    unsigned* Kq = (unsigned*)(ws + off); off += kq_bytes;
    float* scales = (float*)(ws + off); off += sc_bytes;
    unsigned* pz0 = (unsigned*)(ws + off); off += pz_bytes;
    unsigned* pz1 = (unsigned*)(ws + off); off += pz_bytes;
    int* flags = (int*)(ws + off); off += fl_bytes;
    float* scz = (float*)(ws + off);

    quant4_kernel<<<NN, 256, 0, stream>>>(K, Kq, scales);
    prep_kernel<<<1, 256, 0, stream>>>(z_in, pz0, flags, scz);
    persist_kernel<<<NBLK, TPB, 0, stream>>>(Kq, scales, z_in, pz0, pz1, flags,
                                             scz, omega_p, dt_p, out);
  } else {
    float* zb0 = (float*)ws;
    float* zb1 = zb0 + NN * 2;
    const float* src = z_in;
    for (int s = 0; s < STEPS; ++s) {
      float* dst = (s & 1) ? zb1 : zb0;
      step_f32<<<NN / 8, 256, 0, stream>>>(K, src, dst, omega_p, dt_p);
      src = dst;
    }
    finalize_kernel<<<(NN + 255) / 256, 256, 0, stream>>>(src, out);
  }
}

// Round 11
// 664.931 us; speedup vs baseline: 1.8209x; 1.8209x over previous
//
#include <hip/hip_runtime.h>

#define NN 8192
#define STEPS 128
#define CLAMP_V 0.999f
#define WPR 1024   // packed 4-bit words per row (8192/8)
#define NBLK 256
#define TPB 1024

typedef unsigned long long ull;

#if __has_builtin(__builtin_amdgcn_sdot4)
#define DOT4(a, b, c) __builtin_amdgcn_sdot4((int)(a), (int)(b), (c), false)
#else
__device__ __forceinline__ int dot4_fb(int a, int b, int c) {
#pragma unroll
  for (int i = 0; i < 4; ++i)
    c += ((int)(signed char)(a >> (8 * i))) * ((int)(signed char)(b >> (8 * i)));
  return c;
}
#define DOT4(a, b, c) dot4_fb((int)(a), (int)(b), (c))
#endif

#if __has_builtin(__builtin_amdgcn_perm)
#define PERM(a, b, s) __builtin_amdgcn_perm((a), (b), (s))
#else
__device__ __forceinline__ unsigned perm_fb(unsigned a, unsigned b, unsigned s) {
  unsigned long long v = ((unsigned long long)a << 32) | b;
  unsigned r = 0;
#pragma unroll
  for (int i = 0; i < 4; ++i) r |= ((unsigned)(v >> (8 * ((s >> (8 * i)) & 7))) & 0xFF) << (8 * i);
  return r;
}
#define PERM(a, b, s) perm_fb((a), (b), (s))
#endif

// =============== int4 quantization -> per-wave-contiguous layout (R7) ===============
// Nibble order per word: {c0,c4,c1,c5,c2,c6,c3,c7}; lo=(w<<4)&0xF0F0F0F0={c0..c3}*16,
// hi=w&0xF0F0F0F0={c4..c7}*16. scales[row]=rowmax/(7*16).
// Wave wv of block b owns rows 32b+2wv (ab=0), +1 (ab=1); lane l uses word seg*64+l.
// Lane's 32 words contiguous: Kq[((b*16+wv)*64 + l)*32 + ab*16 + seg]
// => per-step K reload = 8 coalesced dwordx4 per lane.
__global__ __launch_bounds__(256) void quant4_kernel(const float* __restrict__ K,
                                                     unsigned* __restrict__ Kq,
                                                     float* __restrict__ scales) {
  const int row = blockIdx.x;
  const int tid = threadIdx.x;
  const int wave = tid >> 6, lane = tid & 63;
  const size_t base = (size_t)row * NN;

  float4 va[4], vb[4];
  float mx = 0.f;
#pragma unroll
  for (int g = 0; g < 4; ++g) {
    const size_t o = base + (size_t)(g * 256 + tid) * 8;
    va[g] = *(const float4*)(K + o);
    vb[g] = *(const float4*)(K + o + 4);
    mx = fmaxf(mx, fmaxf(fmaxf(fabsf(va[g].x), fabsf(va[g].y)),
                         fmaxf(fabsf(va[g].z), fabsf(va[g].w))));
    mx = fmaxf(mx, fmaxf(fmaxf(fabsf(vb[g].x), fabsf(vb[g].y)),
                         fmaxf(fabsf(vb[g].z), fabsf(vb[g].w))));
  }
#pragma unroll
  for (int off = 32; off > 0; off >>= 1) mx = fmaxf(mx, __shfl_xor(mx, off));
  __shared__ float wm[4];
  if (lane == 0) wm[wave] = mx;
  __syncthreads();
  mx = fmaxf(fmaxf(wm[0], wm[1]), fmaxf(wm[2], wm[3]));

  const float inv = (mx > 0.f) ? 7.f / mx : 0.f;
  if (tid == 0) scales[row] = mx / 112.f;   // rowmax/(7*16)

  const int b = row >> 5, wv = (row & 31) >> 1, ab = row & 1;

#pragma unroll
  for (int g = 0; g < 4; ++g) {
    int qa[4], qb[4];
    const float a4[4] = {va[g].x, va[g].y, va[g].z, va[g].w};
    const float b4[4] = {vb[g].x, vb[g].y, vb[g].z, vb[g].w};
#pragma unroll
    for (int i = 0; i < 4; ++i) {
      qa[i] = max(-7, min(7, __float2int_rn(a4[i] * inv)));
      qb[i] = max(-7, min(7, __float2int_rn(b4[i] * inv)));
    }
    unsigned w = 0;
#pragma unroll
    for (int i = 0; i < 4; ++i) {
      w |= ((unsigned)(qa[i] & 0xF)) << (8 * i);        // c_i at nibble 2i
      w |= ((unsigned)(qb[i] & 0xF)) << (8 * i + 4);    // c_{4+i} at nibble 2i+1
    }
    const int widx = g * 256 + tid;
    const int seg = widx >> 6, l = widx & 63;
    Kq[(size_t)((b * 16 + wv) * 64 + l) * 32 + ab * 16 + seg] = w;
  }
}

// =============== prep: build tagged plane_0; seed tz1 with impossible tag ===============
// Tagged word for pair p (rows 2p,2p+1): re0|im0<<8|re1<<16|im1<<24 | tag<<32.
__global__ __launch_bounds__(256) void prep_kernel(const float* __restrict__ z,
                                                   ull* __restrict__ tz0,
                                                   ull* __restrict__ tz1,
                                                   float* __restrict__ scz) {
  const int tid = threadIdx.x;
  const int wave = tid >> 6, lane = tid & 63;
  float4 buf[16];
  float mx = 0.f;
#pragma unroll
  for (int j = 0; j < 16; ++j) {
    buf[j] = *(const float4*)(z + tid * 64 + j * 4);
    mx = fmaxf(mx, fmaxf(fmaxf(fabsf(buf[j].x), fabsf(buf[j].y)),
                         fmaxf(fabsf(buf[j].z), fabsf(buf[j].w))));
  }
#pragma unroll
  for (int off = 32; off > 0; off >>= 1) mx = fmaxf(mx, __shfl_xor(mx, off));
  __shared__ float wm[4];
  if (lane == 0) wm[wave] = mx;
  __syncthreads();
  mx = fmaxf(fmaxf(wm[0], wm[1]), fmaxf(wm[2], wm[3]));
  const float q = (mx > 0.f) ? 127.f / mx : 0.f;
  if (tid == 0) scz[0] = mx / 127.f;
#pragma unroll
  for (int j = 0; j < 16; ++j) {
    const int p = tid * 16 + j;
    const unsigned a = (unsigned)(max(-127, min(127, __float2int_rn(buf[j].x * q)))) & 0xFFu;
    const unsigned b = (unsigned)(max(-127, min(127, __float2int_rn(buf[j].y * q)))) & 0xFFu;
    const unsigned c = (unsigned)(max(-127, min(127, __float2int_rn(buf[j].z * q)))) & 0xFFu;
    const unsigned d = (unsigned)(max(-127, min(127, __float2int_rn(buf[j].w * q)))) & 0xFFu;
    tz0[p] = (ull)(a | (b << 8) | (c << 16) | (d << 24));  // tag 0
    tz1[p] = 0xFFFFFFFFull << 32;                           // never matches
  }
}

// =============== persistent kernel: R7 skeleton + COLLECTIVE publish ===============
// 256 blocks x 1024 thr (16 waves). Wave w owns pair 16b+w (rows 32b+2w,+1).
// Identical to R7 except the publish: instead of 16 scattered per-wave 8B agent
// stores (which hit ONE 128B LLC line at 16 different times, ping-ponging it
// against ~256 polling waves -> measured 4x write amplification, WRITE_SIZE
// 16.3MB vs 4MB payload), each wave parks its packed u32 in LDS; after the
// (pre-existing) end-of-loop barrier, wave 0 lanes 0-15 store the block's 16
// tagged u64s as ONE coalesced 128B transaction. Tags still ride with data
// (1-hop protocol preserved); no new hops, no new barriers.
// Safety induction unchanged from R3-R7.
__global__ __launch_bounds__(TPB, 4)
void persist_kernel(const unsigned* __restrict__ Kq, const float* __restrict__ scales,
                    const float* __restrict__ z_in,
                    ull* __restrict__ tz0, ull* __restrict__ tz1,
                    const float* __restrict__ scz_p,
                    const float* __restrict__ omega_p, const float* __restrict__ dt_p,
                    float* __restrict__ out) {
  const int tid = threadIdx.x;
  const int wave = tid >> 6, lane = tid & 63;
  const int rowA = blockIdx.x * 32 + wave * 2;

  __shared__ ull lds_re[1024];   // 8 KiB re plane (single buffer)
  __shared__ ull lds_im[1024];   // 8 KiB im plane
  __shared__ unsigned pub[16];   // per-wave packed payload for collective publish

  // ---- per-lane z state: even lanes own row A, odd lanes own row B ----
  const int isB = lane & 1;
  float zr_s = z_in[2 * rowA + 2 * isB];
  float zi_s = z_in[2 * rowA + 2 * isB + 1];
  const float mySc = scales[rowA + isB];
  const float omega = *omega_p, dt = *dt_p;
  const float inv2n = 1.0f / (2.0f * (float)NN);
  const float sz0 = *scz_p;

  const int j = wave * 64 + lane;   // staged word (pairs 4j..4j+3)
  // lane's 32 K-words (rowA segs 0..15, rowB segs 0..15), contiguous
  const uint4* kp = (const uint4*)(Kq + (size_t)((blockIdx.x * 16 + wave) * 64 + lane) * 32);

  for (int s = 0; s < STEPS; ++s) {
    const ull* tzc = (s & 1) ? tz1 : tz0;   // plane_s
    const unsigned tagw = (unsigned)s;

    // ---- issue K prefetch first: completes while we wait in the poll ----
    uint4 kv[8];
#pragma unroll
    for (int r = 0; r < 8; ++r) kv[r] = kp[r];

    // ---- poll own 4 tagged words (selective re-read, short sleep) ----
    ull t0 = 0, t1 = 0, t2 = 0, t3 = 0;
    {
      const ull* p4 = tzc + 4 * j;
      bool k0 = false, k1 = false, k2 = false, k3 = false;
      for (;;) {
        if (!k0) { t0 = __hip_atomic_load(p4 + 0, __ATOMIC_RELAXED, __HIP_MEMORY_SCOPE_AGENT);
                   k0 = ((unsigned)(t0 >> 32) == tagw); }
        if (!k1) { t1 = __hip_atomic_load(p4 + 1, __ATOMIC_RELAXED, __HIP_MEMORY_SCOPE_AGENT);
                   k1 = ((unsigned)(t1 >> 32) == tagw); }
        if (!k2) { t2 = __hip_atomic_load(p4 + 2, __ATOMIC_RELAXED, __HIP_MEMORY_SCOPE_AGENT);
                   k2 = ((unsigned)(t2 >> 32) == tagw); }
        if (!k3) { t3 = __hip_atomic_load(p4 + 3, __ATOMIC_RELAXED, __HIP_MEMORY_SCOPE_AGENT);
                   k3 = ((unsigned)(t3 >> 32) == tagw); }
        if (__all(k0 && k1 && k2 && k3)) break;
        __builtin_amdgcn_s_sleep(1);   // ~64 cyc detect quantum
      }
    }
    // ---- unpack {re,im,re,im}x4 -> plane words (byte i = row 8j+i) ----
    {
      const unsigned lo0 = (unsigned)t0, lo1 = (unsigned)t1;
      const unsigned lo2 = (unsigned)t2, lo3 = (unsigned)t3;
      const unsigned re0123 = PERM(lo1, lo0, 0x06040200u);
      const unsigned re4567 = PERM(lo3, lo2, 0x06040200u);
      const unsigned im0123 = PERM(lo1, lo0, 0x07050301u);
      const unsigned im4567 = PERM(lo3, lo2, 0x07050301u);
      lds_re[j] = (ull)re0123 | ((ull)re4567 << 32);
      lds_im[j] = (ull)im0123 | ((ull)im4567 << 32);
    }
    __syncthreads();   // SYNC-A: full plane staged

    // ---- dot: both rows, all 16 segs; K from registers ----
    int srA = 0, siA = 0, srB = 0, siB = 0;
#pragma unroll
    for (int seg = 0; seg < 16; ++seg) {
      const ull zr = lds_re[seg * 64 + lane];   // 8B lane stride: conflict-free
      const ull zi = lds_im[seg * 64 + lane];
      const unsigned zrl = (unsigned)zr, zrh = (unsigned)(zr >> 32);
      const unsigned zil = (unsigned)zi, zih = (unsigned)(zi >> 32);
      const uint4 ka4 = kv[seg >> 2];
      const uint4 kb4 = kv[4 + (seg >> 2)];
      const unsigned wA = (seg & 3) == 0 ? ka4.x : (seg & 3) == 1 ? ka4.y
                        : (seg & 3) == 2 ? ka4.z : ka4.w;
      const unsigned wB = (seg & 3) == 0 ? kb4.x : (seg & 3) == 1 ? kb4.y
                        : (seg & 3) == 2 ? kb4.z : kb4.w;
      const unsigned loA = (wA << 4) & 0xF0F0F0F0u, hiA = wA & 0xF0F0F0F0u;
      const unsigned loB = (wB << 4) & 0xF0F0F0F0u, hiB = wB & 0xF0F0F0F0u;
      srA = DOT4(loA, zrl, srA); srA = DOT4(hiA, zrh, srA);
      siA = DOT4(loA, zil, siA); siA = DOT4(hiA, zih, siA);
      srB = DOT4(loB, zrl, srB); srB = DOT4(hiB, zrh, srB);
      siB = DOT4(loB, zil, siB); siB = DOT4(hiB, zih, siB);
    }

    // ---- exact integer wave butterfly -> lane-uniform sums ----
#pragma unroll
    for (int off = 32; off > 0; off >>= 1) {
      srA += __shfl_xor(srA, off); siA += __shfl_xor(siA, off);
      srB += __shfl_xor(srB, off); siB += __shfl_xor(siB, off);
    }

    // ---- lane-split update: even lanes row A, odd lanes row B (same op order) ----
    const int sr = isB ? srB : srA;
    const int si = isB ? siB : siA;
    const float sz = (s == 0) ? sz0 : (1.f / 127.f);
    const float fac = mySc * sz;
    const float Wr = (float)sr * fac, Wi = (float)si * fac;
    const float z2r = zr_s * zr_s - zi_s * zi_s;
    const float z2i = 2.0f * zr_s * zi_s;
    const float t1r = -inv2n * (Wr * z2r + Wi * z2i);
    const float t1i = -inv2n * (Wr * z2i - Wi * z2r);
    float nr = zr_s + dt * (t1r + omega * zr_s + inv2n * Wr);
    float ni = zi_s + dt * (t1i + omega * zi_s + inv2n * Wi);
    const float a = sqrtf(nr * nr + ni * ni);
    if (a >= CLAMP_V) { nr = nr / a * CLAMP_V; ni = ni / a * CLAMP_V; }
    zr_s = nr; zi_s = ni;

    if (s == STEPS - 1) {
      float fr = nr, fi = ni;
      const float n2 = sqrtf(fr * fr + fi * fi);
      if (n2 >= CLAMP_V) { fr = fr / n2 * CLAMP_V; fi = fi / n2 * CLAMP_V; }
      const float frB = __shfl(fr, 1);
      const float fiB = __shfl(fi, 1);
      if (lane == 0) {
        float4 o; o.x = fr; o.y = fi; o.z = frB; o.w = fiB;
        *(float4*)(out + 2 * rowA) = o;   // rows A,B contiguous, 16B-aligned
      }
    } else {
      const unsigned pr = (unsigned)__float2int_rn(nr * 127.f) & 0xFFu;
      const unsigned pi = (unsigned)__float2int_rn(ni * 127.f) & 0xFFu;
      const unsigned half = pr | (pi << 8);      // even: A bytes, odd: B bytes
      const unsigned other = __shfl_xor(half, 1);
      if (lane == 0) pub[wave] = half | (other << 16);
    }
    __syncthreads();   // SYNC-B: pub[] complete; LDS plane reads closed (same
                       // barrier R7 already paid for LDS reuse)

    // ---- collective publish: ONE coalesced 128B store of 16 tagged u64s ----
    if (s < STEPS - 1 && wave == 0 && lane < 16) {
      const ull w = (ull)pub[lane] | ((ull)(unsigned)(s + 1) << 32);
      __hip_atomic_store(((s & 1) ? tz0 : tz1) + 16 * blockIdx.x + lane, w,
                         __ATOMIC_RELAXED, __HIP_MEMORY_SCOPE_AGENT);
    }
  }
}

// =============== f32 fallback (no workspace) ===============
__global__ __launch_bounds__(256, 2)
void step_f32(const float* __restrict__ K,
              const float* __restrict__ z_old, float* __restrict__ z_new,
              const float* __restrict__ omega_p, const float* __restrict__ dt_p) {
  const int tid = threadIdx.x;
  const int wave = tid >> 6, lane = tid & 63;
  const int row0 = blockIdx.x * 8;
  __shared__ float red[4][16];
  float ar[8] = {0, 0, 0, 0, 0, 0, 0, 0};
  float ai[8] = {0, 0, 0, 0, 0, 0, 0, 0};
  const int cbase = wave * 2048 + lane * 8;
#pragma unroll
  for (int it = 0; it < 4; ++it) {
    const int c = cbase + it * 512;
    const float4 zA = *(const float4*)(z_old + 2 * c + 0);
    const float4 zB = *(const float4*)(z_old + 2 * c + 4);
    const float4 zC = *(const float4*)(z_old + 2 * c + 8);
    const float4 zD = *(const float4*)(z_old + 2 * c + 12);
#pragma unroll
    for (int r = 0; r < 8; ++r) {
      const float* kp = K + (size_t)(row0 + r) * NN + c;
      const float4 ka = *(const float4*)kp;
      const float4 kb = *(const float4*)(kp + 4);
      float sr = ar[r], si = ai[r];
      sr = fmaf(ka.x, zA.x, sr); si = fmaf(ka.x, zA.y, si);
      sr = fmaf(ka.y, zA.z, sr); si = fmaf(ka.y, zA.w, si);
      sr = fmaf(ka.z, zB.x, sr); si = fmaf(ka.z, zB.y, si);
      sr = fmaf(ka.w, zB.z, sr); si = fmaf(ka.w, zB.w, si);
      sr = fmaf(kb.x, zC.x, sr); si = fmaf(kb.x, zC.y, si);
      sr = fmaf(kb.y, zC.z, sr); si = fmaf(kb.y, zC.w, si);
      sr = fmaf(kb.z, zD.x, sr); si = fmaf(kb.z, zD.y, si);
      sr = fmaf(kb.w, zD.z, sr); si = fmaf(kb.w, zD.w, si);
      ar[r] = sr; ai[r] = si;
    }
  }
#pragma unroll
  for (int off = 32; off > 0; off >>= 1) {
#pragma unroll
    for (int r = 0; r < 8; ++r) {
      ar[r] += __shfl_xor(ar[r], off);
      ai[r] += __shfl_xor(ai[r], off);
    }
  }
  if (lane == 0) {
#pragma unroll
    for (int r = 0; r < 8; ++r) {
      red[wave][2 * r + 0] = ar[r];
      red[wave][2 * r + 1] = ai[r];
    }
  }
  __syncthreads();
  if (tid < 8) {
    const float Wr = red[0][2 * tid] + red[1][2 * tid] + red[2][2 * tid] + red[3][2 * tid];
    const float Wi = red[0][2 * tid + 1] + red[1][2 * tid + 1] +
                     red[2][2 * tid + 1] + red[3][2 * tid + 1];
    const int row = row0 + tid;
    const float omega = *omega_p;
    const float dt = *dt_p;
    const float inv2n = 1.0f / (2.0f * (float)NN);
    const float zr = z_old[2 * row];
    const float zi = z_old[2 * row + 1];
    const float z2r = zr * zr - zi * zi;
    const float z2i = 2.0f * zr * zi;
    const float t1r = -inv2n * (Wr * z2r + Wi * z2i);
    const float t1i = -inv2n * (Wr * z2i - Wi * z2r);
    float nr = zr + dt * (t1r + omega * zr + inv2n * Wr);
    float ni = zi + dt * (t1i + omega * zi + inv2n * Wi);
    const float a = sqrtf(nr * nr + ni * ni);
    if (a >= CLAMP_V) { nr = nr / a * CLAMP_V; ni = ni / a * CLAMP_V; }
    z_new[2 * row] = nr;
    z_new[2 * row + 1] = ni;
  }
}

__global__ __launch_bounds__(256) void finalize_kernel(const float* __restrict__ z,
                                                       float* __restrict__ out) {
  int i = blockIdx.x * blockDim.x + threadIdx.x;
  if (i < NN) {
    float x = z[2 * i], y = z[2 * i + 1];
    float n = sqrtf(x * x + y * y);
    if (n >= CLAMP_V) { x = x / n * CLAMP_V; y = y / n * CLAMP_V; }
    out[2 * i] = x;
    out[2 * i + 1] = y;
  }
}

extern "C" void kernel_launch(void* const* d_in, const int* in_sizes, int n_in,
                              void* d_out, int out_size, void* d_ws, size_t ws_size,
                              hipStream_t stream) {
  const float* z_in = (const float*)d_in[0];      // [8192,2] f32
  const float* K = (const float*)d_in[1];         // [8192,8192] f32
  const float* omega_p = (const float*)d_in[2];   // scalar f32
  const float* dt_p = (const float*)d_in[3];      // scalar f32
  float* out = (float*)d_out;

  char* ws = (char*)d_ws;
  const size_t kq_bytes = (size_t)NN * WPR * sizeof(unsigned);   // 32 MiB
  const size_t sc_bytes = (size_t)NN * sizeof(float);            // 32 KiB
  const size_t tz_bytes = (size_t)(NN / 2) * sizeof(ull);        // 32 KiB each
  const size_t need = kq_bytes + sc_bytes + 2 * tz_bytes + 256;

  if (ws_size >= need) {
    size_t off = 0;
    unsigned* Kq = (unsigned*)(ws + off); off += kq_bytes;
    float* scales = (float*)(ws + off); off += sc_bytes;
    ull* tz0 = (ull*)(ws + off); off += tz_bytes;
    ull* tz1 = (ull*)(ws + off); off += tz_bytes;
    float* scz = (float*)(ws + off);

    quant4_kernel<<<NN, 256, 0, stream>>>(K, Kq, scales);
    prep_kernel<<<1, 256, 0, stream>>>(z_in, tz0, tz1, scz);
    persist_kernel<<<NBLK, TPB, 0, stream>>>(Kq, scales, z_in, tz0, tz1,
                                             scz, omega_p, dt_p, out);
  } else {
    float* zb0 = (float*)ws;
    float* zb1 = zb0 + NN * 2;
    const float* src = z_in;
    for (int s = 0; s < STEPS; ++s) {
      float* dst = (s & 1) ? zb1 : zb0;
      step_f32<<<NN / 8, 256, 0, stream>>>(K, src, dst, omega_p, dt_p);
      src = dst;
    }
    finalize_kernel<<<(NN + 255) / 256, 256, 0, stream>>>(src, out);
  }
}